// Round 2
// baseline (512.668 us; speedup 1.0000x reference)
//
#include <hip/hip_runtime.h>
#include <hip/hip_bf16.h>

typedef unsigned int u32;
typedef unsigned short u16;
typedef unsigned char u8;

#define L_SEQ 200
#define TILE_L 8

__device__ __forceinline__ float bf2f(u16 h) { return __uint_as_float(((u32)h) << 16); }
__device__ __forceinline__ u16 f2bf(float f) {
    u32 u = __float_as_uint(f);
    return (u16)((u + 0x7FFFu + ((u >> 16) & 1u)) >> 16);  // RNE
}
__device__ __forceinline__ float wave_sumf(float v) {
#pragma unroll
    for (int off = 32; off; off >>= 1) v += __shfl_xor(v, off, 64);
    return v;
}
template <bool F32>
__device__ __forceinline__ float ldf(const void* p, int i) {
    return F32 ? ((const float*)p)[i] : bf2f(((const u16*)p)[i]);
}

// ---- detection ---------------------------------------------------------------
// flags[0]: x_mask encoding bits (bit0: float-ish bytes; bit1: nonzero byte at
//           off%4!=0 -> u8; bit2: nonzero byte at off%4==1 -> 2-byte elems)
// flags[1]: count of emb_table words whose byte1 does NOT look like a bf16
//           sign/exp byte. bf16 -> ~0; f32 (byte1 = mantissa bits) -> ~87% of 2048.
__global__ void zero_flags_kernel(u32* flags) {
    if (threadIdx.x < 2) flags[threadIdx.x] = 0u;
}

__global__ void detect_mask_kernel(const u8* __restrict__ mb, u32* __restrict__ flags, int n4) {
    int tid = blockIdx.x * blockDim.x + threadIdx.x;
    int nth = gridDim.x * blockDim.x;
    u32 c = 0;
    const uint4* p = (const uint4*)mb;
    for (int i = tid; i < n4; i += nth) {
        uint4 w = p[i];
        u32 o = w.x | w.y | w.z | w.w;
        c |= ((o & 0xFEFEFEFEu) ? 1u : 0u) | ((o & 0xFFFFFF00u) ? 2u : 0u) |
             ((o & 0x0000FF00u) ? 4u : 0u);
    }
#pragma unroll
    for (int off = 32; off; off >>= 1) c |= __shfl_xor((int)c, off, 64);
    if ((threadIdx.x & 63) == 0 && c) atomicOr(flags, c);
}

__global__ void detect_f32_kernel(const u32* __restrict__ embw, u32* __restrict__ flags) {
    int i = 64 + blockIdx.x * 256 + threadIdx.x;  // skip all-zero emb row 0
    u32 b1 = (embw[i] >> 8) & 0x7Fu;              // bf16: sign/exp byte (sans sign)
    int f = (b1 == 0u || (b1 >= 0x30u && b1 <= 0x3Fu)) ? 0 : 1;
#pragma unroll
    for (int off = 32; off; off >>= 1) f += __shfl_xor(f, off, 64);
    if ((threadIdx.x & 63) == 0 && f) atomicAdd(&flags[1], (u32)f);
}

// ---- main fused kernel -------------------------------------------------------
// wave-per-sample; streaming (no-max) softmax: att_u >= 0 and tiny -> exp can't
// overflow. Both F32 instantiations are launched; the wrong one exits early.
template <bool F32>
__global__ __launch_bounds__(256, 4) void etna_main(
    const int* __restrict__ x, const void* __restrict__ xmask,
    const void* __restrict__ ob, const void* __restrict__ emb,
    const void* __restrict__ tranW, const void* __restrict__ tranb,
    const void* __restrict__ attW, const void* __restrict__ attb,
    const void* __restrict__ W0, const void* __restrict__ W1, const void* __restrict__ W2,
    void* __restrict__ out, const u32* __restrict__ flags, int Vn) {
    const u32 fl = flags[0];
    const bool isF32 = flags[1] > 1024u;
    if (isF32 != F32) return;  // block-uniform: safe w.r.t. barriers below

    __shared__ u32 Wpk[3][32][64];      // bf16 pair (d=2t,2t+1) of tran_W[a][d][j]
    __shared__ float embl[4][TILE_L][64];
    __shared__ float repl[4][3][64];

    const int tid = threadIdx.x;
    const int wv = tid >> 6;
    const int j = tid & 63;
    const int b = blockIdx.x * 4 + wv;

    for (int i = tid; i < 3 * 32 * 64; i += 256) {
        int a = i >> 11, r = i & 2047, t = r >> 6, jj = r & 63;
        int i0 = a * 4096 + (2 * t) * 64 + jj, i1 = i0 + 64;
        u32 lo, hi;
        if (F32) { lo = f2bf(((const float*)tranW)[i0]); hi = f2bf(((const float*)tranW)[i1]); }
        else     { lo = ((const u16*)tranW)[i0];         hi = ((const u16*)tranW)[i1]; }
        Wpk[a][t][jj] = lo | (hi << 16);
    }
    __syncthreads();

    const float aW0 = ldf<F32>(attW, j), aW1 = ldf<F32>(attW, 64 + j), aW2 = ldf<F32>(attW, 128 + j);
    const float tb0 = ldf<F32>(tranb, j), tb1 = ldf<F32>(tranb, 64 + j), tb2 = ldf<F32>(tranb, 128 + j);
    const float ab0 = ldf<F32>(attb, 0), ab1 = ldf<F32>(attb, 1), ab2 = ldf<F32>(attb, 2);

    const int esz = (fl & 1u) ? ((fl & 4u) ? 2 : 4) : ((fl & 2u) ? 1 : 4);

    int len = 0;
    {
        int mbase = b * L_SEQ;
#pragma unroll
        for (int c = 0; c < 4; ++c) {
            int l = c * 64 + j;
            bool v = false;
            if (l < L_SEQ) {
                int off = mbase + l;
                if (esz == 1)      v = ((const u8*)xmask)[off] != 0;
                else if (esz == 2) v = ((const u16*)xmask)[off] != 0;
                else               v = ((const u32*)xmask)[off] != 0;
            }
            len += (int)__popcll(__ballot(v));
        }
    }

    const int* xrow = x + b * L_SEQ;
    float den0 = 0.f, den1 = 0.f, den2 = 0.f;
    float num0 = 0.f, num1 = 0.f, num2 = 0.f;

    for (int l0 = 0; l0 < len; l0 += TILE_L) {
#pragma unroll
        for (int li = 0; li < TILE_L; ++li) {
            int l = l0 + li;
            int idx = (l < len) ? xrow[l] : 0;
            idx = max(0, min(idx, Vn - 1));      // defensive clamp
            embl[wv][li][j] = ldf<F32>(emb, idx * 64 + j);
        }
        float acc[TILE_L][3];
#pragma unroll
        for (int li = 0; li < TILE_L; ++li) { acc[li][0] = tb0; acc[li][1] = tb1; acc[li][2] = tb2; }
#pragma unroll 8
        for (int t = 0; t < 32; ++t) {
            u32 wp0 = Wpk[0][t][j], wp1 = Wpk[1][t][j], wp2 = Wpk[2][t][j];
            float w0a = __uint_as_float(wp0 << 16), w0b = __uint_as_float(wp0 & 0xFFFF0000u);
            float w1a = __uint_as_float(wp1 << 16), w1b = __uint_as_float(wp1 & 0xFFFF0000u);
            float w2a = __uint_as_float(wp2 << 16), w2b = __uint_as_float(wp2 & 0xFFFF0000u);
#pragma unroll
            for (int li = 0; li < TILE_L; ++li) {
                float2 e2 = *(const float2*)&embl[wv][li][2 * t];
                acc[li][0] = fmaf(e2.x, w0a, fmaf(e2.y, w0b, acc[li][0]));
                acc[li][1] = fmaf(e2.x, w1a, fmaf(e2.y, w1b, acc[li][1]));
                acc[li][2] = fmaf(e2.x, w2a, fmaf(e2.y, w2b, acc[li][2]));
            }
        }
#pragma unroll
        for (int li = 0; li < TILE_L; ++li) {
            int l = l0 + li;
            float e0 = fmaxf(acc[li][0], 0.f);
            float e1 = fmaxf(acc[li][1], 0.f);
            float e2v = fmaxf(acc[li][2], 0.f);
            float p0 = wave_sumf(e0 * aW0);
            float p1 = wave_sumf(e1 * aW1);
            float p2 = wave_sumf(e2v * aW2);
            float u0 = fmaxf(p0 + ab0, 0.f);
            float u1 = fmaxf(p1 + ab1, 0.f);
            float u2 = fmaxf(p2 + ab2, 0.f);
            bool valid = (l < len);
            float s0 = valid ? exp2f(u0 * 1.44269504088896f) : 0.f;
            float s1 = valid ? exp2f(u1 * 1.44269504088896f) : 0.f;
            float s2 = valid ? exp2f(u2 * 1.44269504088896f) : 0.f;
            den0 += s0; den1 += s1; den2 += s2;
            num0 = fmaf(s0, e0, num0);
            num1 = fmaf(s1, e1, num1);
            num2 = fmaf(s2, e2v, num2);
        }
    }

    // den >= 1 when len >= 1; guard keeps any residual bug finite (not NaN)
    repl[wv][0][j] = tanhf(num0 / fmaxf(den0, 1e-20f));
    repl[wv][1][j] = tanhf(num1 / fmaxf(den1, 1e-20f));
    repl[wv][2][j] = tanhf(num2 / fmaxf(den2, 1e-20f));

    // interleave u[3d+a] = rep[a][d]; segment s -> u[64s:64s+64] @ Ws
    float outv = 0.f;
    {
        int g = j; float v = repl[wv][g % 3][g / 3];
#pragma unroll
        for (int k = 0; k < 2; ++k) {
            float p = wave_sumf(v * ldf<F32>(W0, j * 2 + k));
            if (j == k) outv = p;
        }
    }
    {
        int g = 64 + j; float v = repl[wv][g % 3][g / 3];
#pragma unroll
        for (int k = 0; k < 6; ++k) {
            float p = wave_sumf(v * ldf<F32>(W1, j * 6 + k));
            if (j == 2 + k) outv = p;
        }
    }
    {
        int g = 128 + j; float v = repl[wv][g % 3][g / 3];
#pragma unroll
        for (int k = 0; k < 10; ++k) {
            float p = wave_sumf(v * ldf<F32>(W2, j * 10 + k));
            if (j == 8 + k) outv = p;
        }
    }
    if (j < 18) {
        float o = outv * ldf<F32>(ob, b * 18 + j);
        if (F32) ((float*)out)[b * 18 + j] = o;
        else     ((u16*)out)[b * 18 + j] = f2bf(o);
    }
}

extern "C" void kernel_launch(void* const* d_in, const int* in_sizes, int n_in,
                              void* d_out, int out_size, void* d_ws, size_t ws_size,
                              hipStream_t stream) {
    const int* x = (const int*)d_in[0];
    const void* xmask = d_in[1];
    // d_in[2] = y : unused
    const void* ob = d_in[3];
    const void* emb = d_in[4];
    const void* tranW = d_in[5];
    const void* tranb = d_in[6];
    const void* attW = d_in[7];
    const void* attb = d_in[8];
    const void* W0 = d_in[9];
    const void* W1 = d_in[10];
    const void* W2 = d_in[11];
    u32* flags = (u32*)d_ws;

    const int Bn = in_sizes[0] / L_SEQ;   // 4096
    const int n4 = (Bn * L_SEQ) / 16;     // uint4 words of the mask scan
    const int Vn = in_sizes[4] / 64;      // vocab rows

    zero_flags_kernel<<<1, 64, 0, stream>>>(flags);
    detect_mask_kernel<<<128, 256, 0, stream>>>((const u8*)xmask, flags, n4);
    detect_f32_kernel<<<8, 256, 0, stream>>>((const u32*)emb, flags);
    etna_main<false><<<Bn / 4, 256, 0, stream>>>(x, xmask, ob, emb, tranW, tranb, attW,
                                                 attb, W0, W1, W2, d_out, flags, Vn);
    etna_main<true><<<Bn / 4, 256, 0, stream>>>(x, xmask, ob, emb, tranW, tranb, attW,
                                                attb, W0, W1, W2, d_out, flags, Vn);
}

// Round 6
// 178.706 us; speedup vs baseline: 2.8688x; 2.8688x over previous
//
#include <hip/hip_runtime.h>

typedef unsigned int u32;
typedef unsigned short u16;
typedef unsigned char u8;
typedef unsigned long long u64;

typedef __attribute__((ext_vector_type(8))) short bf16x8;
typedef __attribute__((ext_vector_type(4))) float f32x4;

#define L_SEQ 200

__device__ __forceinline__ float bf2f(u16 h) { return __uint_as_float(((u32)h) << 16); }
__device__ __forceinline__ u16 f2bf(float f) {
    u32 u = __float_as_uint(f);
    return (u16)((u + 0x7FFFu + ((u >> 16) & 1u)) >> 16);  // RNE
}
__device__ __forceinline__ float wave_sumf(float v) {
#pragma unroll
    for (int off = 32; off; off >>= 1) v += __shfl_xor(v, off, 64);
    return v;
}
template <bool F32>
__device__ __forceinline__ float ldf(const void* p, int i) {
    return F32 ? ((const float*)p)[i] : bf2f(((const u16*)p)[i]);
}

// ---- detection (R2-proven) --------------------------------------------------
// flags[0]: x_mask encoding bits; flags[1]: count of emb words whose byte1 is
// NOT a plausible bf16 sign/exp byte (bf16 -> ~0; f32 mantissa bytes -> ~87%).
__global__ void zero_flags_kernel(u32* flags) {
    if (threadIdx.x < 2) flags[threadIdx.x] = 0u;
}

__global__ void detect_mask_kernel(const u8* __restrict__ mb, u32* __restrict__ flags, int n4) {
    int tid = blockIdx.x * blockDim.x + threadIdx.x;
    int nth = gridDim.x * blockDim.x;
    u32 c = 0;
    const uint4* p = (const uint4*)mb;
    for (int i = tid; i < n4; i += nth) {
        uint4 w = p[i];
        u32 o = w.x | w.y | w.z | w.w;
        c |= ((o & 0xFEFEFEFEu) ? 1u : 0u) | ((o & 0xFFFFFF00u) ? 2u : 0u) |
             ((o & 0x0000FF00u) ? 4u : 0u);
    }
#pragma unroll
    for (int off = 32; off; off >>= 1) c |= (u32)__shfl_xor((int)c, off, 64);
    if ((threadIdx.x & 63) == 0 && c) atomicOr(flags, c);
}

__global__ void detect_f32_kernel(const u32* __restrict__ embw, u32* __restrict__ flags) {
    int i = 64 + blockIdx.x * 256 + threadIdx.x;  // skip all-zero emb row 0
    u32 b1 = (embw[i] >> 8) & 0x7Fu;
    int f = (b1 == 0u || (b1 >= 0x30u && b1 <= 0x3Fu)) ? 0 : 1;
#pragma unroll
    for (int off = 32; off; off >>= 1) f += __shfl_xor(f, off, 64);
    if ((threadIdx.x & 63) == 0 && f) atomicAdd(&flags[1], (u32)f);
}

// ---- main kernel: wave = 1 sample; MFMA e-tiles; in-wave softmax ------------
// A-frags: lane (col,g) loads emb row xrow[l0+col] dims [g*8,g*8+8) and
// [32+g*8,+8) straight from global (float4 for f32), packs to bf16.
// B-frags: tran_W staged once/block to LDS in B-frag order, held in 96 VGPRs.
// C/D layout (m89): col=lane&15 (output dim block c*16+col), row=4*(lane>>4)+reg
// (token). Streaming no-max softmax (logits >= 0, bounded). All reductions and
// the epilogue are the R2-proven in-wave patterns.
template <bool F32>
__global__ __launch_bounds__(256, 2) void etna_mfma(
    const int* __restrict__ x, const void* __restrict__ xmask,
    const void* __restrict__ ob, const void* __restrict__ emb,
    const void* __restrict__ tranW, const void* __restrict__ tranb,
    const void* __restrict__ attW, const void* __restrict__ attb,
    const void* __restrict__ W0, const void* __restrict__ W1, const void* __restrict__ W2,
    void* __restrict__ out, const u32* __restrict__ flags, int Vn) {
    const u32 fl = flags[0];
    const bool isF32 = flags[1] > 1024u;
    if (isF32 != F32) return;  // grid-uniform; no barrier crossed yet

    __shared__ __align__(16) short Wst[12288];  // B-frags [a][c][kh][lane][8]
    __shared__ float repl[4][3][64];

    const int tid = threadIdx.x;
    const int wv = tid >> 6;
    const int lane = tid & 63;
    const int col = lane & 15;  // A row m / B+D col n
    const int g = lane >> 4;    // k-chunk / D row group
    const int b = blockIdx.x * 4 + wv;

    // stage tran_W -> B-frag layout: element j of frag (a,c,kh,lane) is
    // tranW[a][k = kh*32 + (lane>>4)*8 + j][n = c*16 + (lane&15)]
    for (int it = tid; it < 12288; it += 256) {
        int jj = it & 7;
        int ln = (it >> 3) & 63;
        int kh = (it >> 9) & 1;
        int c = (it >> 10) & 3;
        int a = it >> 12;
        int k = kh * 32 + (ln >> 4) * 8 + jj;
        int n = c * 16 + (ln & 15);
        int src = a * 4096 + k * 64 + n;
        Wst[it] = F32 ? (short)f2bf(((const float*)tranW)[src]) : ((const short*)tranW)[src];
    }
    __syncthreads();

    bf16x8 Bf[3][4][2];
#pragma unroll
    for (int a = 0; a < 3; ++a)
#pragma unroll
        for (int c = 0; c < 4; ++c)
#pragma unroll
            for (int kh = 0; kh < 2; ++kh)
                Bf[a][c][kh] = *(const bf16x8*)&Wst[(((a * 4 + c) * 2 + kh) * 64 + lane) * 8];

    const int esz = (fl & 1u) ? ((fl & 4u) ? 2 : 4) : ((fl & 2u) ? 1 : 4);

    // prefix length (per-wave sample)
    int len = 0;
    {
        int mbase = b * L_SEQ;
#pragma unroll
        for (int c4 = 0; c4 < 4; ++c4) {
            int l = c4 * 64 + lane;
            bool v = false;
            if (l < L_SEQ) {
                int off = mbase + l;
                if (esz == 1)      v = ((const u8*)xmask)[off] != 0;
                else if (esz == 2) v = ((const u16*)xmask)[off] != 0;
                else               v = ((const u32*)xmask)[off] != 0;
            }
            len += (int)__popcll(__ballot(v));
        }
    }

    // per-lane constants in C-layout (dim = c*16+col)
    float TB[3][4], AW[3][4], AB[3];
#pragma unroll
    for (int a = 0; a < 3; ++a) {
#pragma unroll
        for (int c = 0; c < 4; ++c) {
            TB[a][c] = ldf<F32>(tranb, a * 64 + c * 16 + col);
            AW[a][c] = ldf<F32>(attW, a * 64 + c * 16 + col);
        }
        AB[a] = ldf<F32>(attb, a);
    }

    float NUM[3][4] = {{0.f}};
    float DEN[3] = {0.f, 0.f, 0.f};
    const float LOG2E = 1.44269504088896f;
    const int* xrow = x + b * L_SEQ;

    for (int l0 = 0; l0 < len; l0 += 16) {
        int l = l0 + col;
        int idx = (l < len) ? xrow[l] : 0;  // emb row 0 is all zeros
        idx = max(0, min(idx, Vn - 1));
        bf16x8 a0, a1;
        if (F32) {
            const float4* ep4 = (const float4*)((const float*)emb + (size_t)idx * 64);
            float4 q0 = ep4[2 * g], q1 = ep4[2 * g + 1];      // dims g*8 .. g*8+7
            float4 q2 = ep4[8 + 2 * g], q3 = ep4[9 + 2 * g];  // dims 32+g*8 ..
            a0[0] = (short)f2bf(q0.x); a0[1] = (short)f2bf(q0.y);
            a0[2] = (short)f2bf(q0.z); a0[3] = (short)f2bf(q0.w);
            a0[4] = (short)f2bf(q1.x); a0[5] = (short)f2bf(q1.y);
            a0[6] = (short)f2bf(q1.z); a0[7] = (short)f2bf(q1.w);
            a1[0] = (short)f2bf(q2.x); a1[1] = (short)f2bf(q2.y);
            a1[2] = (short)f2bf(q2.z); a1[3] = (short)f2bf(q2.w);
            a1[4] = (short)f2bf(q3.x); a1[5] = (short)f2bf(q3.y);
            a1[6] = (short)f2bf(q3.z); a1[7] = (short)f2bf(q3.w);
        } else {
            const bf16x8* ep = (const bf16x8*)((const u16*)emb + (size_t)idx * 64);
            a0 = ep[g];
            a1 = ep[4 + g];
        }

#pragma unroll
        for (int a = 0; a < 3; ++a) {
            f32x4 E[4];
#pragma unroll
            for (int c = 0; c < 4; ++c) {
                f32x4 cc = {TB[a][c], TB[a][c], TB[a][c], TB[a][c]};
                cc = __builtin_amdgcn_mfma_f32_16x16x32_bf16(a0, Bf[a][c][0], cc, 0, 0, 0);
                cc = __builtin_amdgcn_mfma_f32_16x16x32_bf16(a1, Bf[a][c][1], cc, 0, 0, 0);
                E[c].x = fmaxf(cc.x, 0.f);
                E[c].y = fmaxf(cc.y, 0.f);
                E[c].z = fmaxf(cc.z, 0.f);
                E[c].w = fmaxf(cc.w, 0.f);
            }
            float p0 = E[0].x * AW[a][0] + E[1].x * AW[a][1] + E[2].x * AW[a][2] + E[3].x * AW[a][3];
            float p1 = E[0].y * AW[a][0] + E[1].y * AW[a][1] + E[2].y * AW[a][2] + E[3].y * AW[a][3];
            float p2 = E[0].z * AW[a][0] + E[1].z * AW[a][1] + E[2].z * AW[a][2] + E[3].z * AW[a][3];
            float p3 = E[0].w * AW[a][0] + E[1].w * AW[a][1] + E[2].w * AW[a][2] + E[3].w * AW[a][3];
#pragma unroll
            for (int off = 1; off <= 8; off <<= 1) {  // sum 16 cols within group
                p0 += __shfl_xor(p0, off, 64);
                p1 += __shfl_xor(p1, off, 64);
                p2 += __shfl_xor(p2, off, 64);
                p3 += __shfl_xor(p3, off, 64);
            }
            int lrow = l0 + 4 * g;
            float u0 = fmaxf(p0 + AB[a], 0.f);
            float u1 = fmaxf(p1 + AB[a], 0.f);
            float u2 = fmaxf(p2 + AB[a], 0.f);
            float u3 = fmaxf(p3 + AB[a], 0.f);
            float s0 = (lrow + 0 < len) ? exp2f(u0 * LOG2E) : 0.f;
            float s1 = (lrow + 1 < len) ? exp2f(u1 * LOG2E) : 0.f;
            float s2 = (lrow + 2 < len) ? exp2f(u2 * LOG2E) : 0.f;
            float s3 = (lrow + 3 < len) ? exp2f(u3 * LOG2E) : 0.f;
            DEN[a] += s0 + s1 + s2 + s3;
#pragma unroll
            for (int c = 0; c < 4; ++c)
                NUM[a][c] += s0 * E[c].x + s1 * E[c].y + s2 * E[c].z + s3 * E[c].w;
        }
    }

    // fold the 4 row-groups -> full sums in every lane; rep -> per-wave LDS
#pragma unroll
    for (int a = 0; a < 3; ++a) {
        float d = DEN[a];
        d += __shfl_xor(d, 16, 64);
        d += __shfl_xor(d, 32, 64);
        float rden = 1.0f / fmaxf(d, 1e-20f);  // den >= 1 when len >= 1
#pragma unroll
        for (int c = 0; c < 4; ++c) {
            float v = NUM[a][c];
            v += __shfl_xor(v, 16, 64);
            v += __shfl_xor(v, 32, 64);
            if (g == 0) repl[wv][a][c * 16 + col] = tanhf(v * rden);
        }
    }
    // same-wave write->read, float/float (R2-proven pattern; DS is in-order)

    // epilogue (R2-proven): u[3d+a]=rep[a][d]; segment s -> u[64s:64s+64] @ Ws
    float outv = 0.f;
    {
        int gg = lane; float v = repl[wv][gg % 3][gg / 3];
#pragma unroll
        for (int k = 0; k < 2; ++k) {
            float p = wave_sumf(v * ldf<F32>(W0, lane * 2 + k));
            if (lane == k) outv = p;
        }
    }
    {
        int gg = 64 + lane; float v = repl[wv][gg % 3][gg / 3];
#pragma unroll
        for (int k = 0; k < 6; ++k) {
            float p = wave_sumf(v * ldf<F32>(W1, lane * 6 + k));
            if (lane == 2 + k) outv = p;
        }
    }
    {
        int gg = 128 + lane; float v = repl[wv][gg % 3][gg / 3];
#pragma unroll
        for (int k = 0; k < 10; ++k) {
            float p = wave_sumf(v * ldf<F32>(W2, lane * 10 + k));
            if (lane == 8 + k) outv = p;
        }
    }
    if (lane < 18) {
        float o = outv * ldf<F32>(ob, b * 18 + lane);
        if (F32) ((float*)out)[b * 18 + lane] = o;
        else     ((u16*)out)[b * 18 + lane] = f2bf(o);
    }
}

extern "C" void kernel_launch(void* const* d_in, const int* in_sizes, int n_in,
                              void* d_out, int out_size, void* d_ws, size_t ws_size,
                              hipStream_t stream) {
    const int* x = (const int*)d_in[0];
    const void* xmask = d_in[1];
    // d_in[2] = y : unused
    const void* ob = d_in[3];
    const void* emb = d_in[4];
    const void* tranW = d_in[5];
    const void* tranb = d_in[6];
    const void* attW = d_in[7];
    const void* attb = d_in[8];
    const void* W0 = d_in[9];
    const void* W1 = d_in[10];
    const void* W2 = d_in[11];
    u32* flags = (u32*)d_ws;

    const int Bn = in_sizes[0] / L_SEQ;  // 4096
    const int n4 = (Bn * L_SEQ) / 16;    // uint4 words (B*L bytes, safe all widths)
    const int Vn = in_sizes[4] / 64;     // vocab rows

    zero_flags_kernel<<<1, 64, 0, stream>>>(flags);
    detect_mask_kernel<<<128, 256, 0, stream>>>((const u8*)xmask, flags, n4);
    detect_f32_kernel<<<8, 256, 0, stream>>>((const u32*)emb, flags);
    etna_mfma<false><<<Bn / 4, 256, 0, stream>>>(x, xmask, ob, emb, tranW, tranb, attW,
                                                 attb, W0, W1, W2, d_out, flags, Vn);
    etna_mfma<true><<<Bn / 4, 256, 0, stream>>>(x, xmask, ob, emb, tranW, tranb, attW,
                                                attb, W0, W1, W2, d_out, flags, Vn);
}